// Round 7
// baseline (206.965 us; speedup 1.0000x reference)
//
#include <hip/hip_runtime.h>
#include <hip/hip_bf16.h>
#include <stdint.h>

// B=1024, N=16, D=64, H=64, A=64 -> 16384 nodes. All tensors fp32.
#define NNODE 16384
#define TAU_ 0.01f
#define EPSG 1e-10f

// ---- workspace layout (float offsets); total 1,114,112 floats = 4.25 MB ----
#define OFF_WENC 0
#define OFF_BENC 4096
#define OFF_WIHF_H 4160      // 192x128 bf16 = 24576 ushort = 12288 fl
#define OFF_WIHF_L 16448
#define OFF_WHHF_H 28736     // 192x64 bf16 hi
#define OFF_BIHF 41024
#define OFF_BHHF 41216
#define OFF_WIHB_H 41408
#define OFF_WIHB_L 53696
#define OFF_WHHB_H 65984
#define OFF_BIHB 78272
#define OFF_BHHB 78464
#define OFF_WHARD 78656
#define OFF_BHARD 78912
// bf16 hi/lo splits for k_attn MFMA (reuse old f32 Wq/Wk/Wv/Wihc/Whhc slots)
#define OFF_WQT_H 78914      // Wq^T 64x64: 4096 ushort = 2048 fl
#define OFF_WQT_L 80962
#define OFF_WKT_H 83010
#define OFF_WKT_L 85058
#define OFF_WVT_H 87106
#define OFF_WVT_L 89154
#define OFF_BV 91202
#define OFF_WIHC_H 91266     // 192x64: 12288 ushort = 6144 fl
#define OFF_WIHC_L 97410
#define OFF_WHHC_H 103554
#define OFF_WHHC_L 109698
#define OFF_BIHC 115842
#define OFF_BHHC 116034
#define OFF_WENCT_H 118784   // Wenc^T bf16 hi: 64x64
#define OFF_WENCT_L 120832
#define OFF_YF 131072
#define OFF_YB (OFF_YF + 491520)
#define WS_FLOATS (OFF_YB + 491520)

typedef float  v4f __attribute__((ext_vector_type(4)));
typedef short  v8s __attribute__((ext_vector_type(8)));

// v_rcp_f32 (1-ulp approx) instead of precise fp32 division (R6: -31 us).
__device__ __forceinline__ float rcpf(float x){ return __builtin_amdgcn_rcpf(x); }
__device__ __forceinline__ float sigf(float x){ return rcpf(1.0f + __expf(-x)); }
__device__ __forceinline__ float tanhfast(float x){ return 1.0f - 2.0f*rcpf(__expf(2.0f*x)+1.0f); }
__device__ __forceinline__ unsigned short f2bf(float f){
  __hip_bfloat16 h = __float2bfloat16(f);
  return *reinterpret_cast<unsigned short*>(&h);
}
__device__ __forceinline__ float bf2f(unsigned short u){
  union { unsigned int i; float f; } v; v.i = ((unsigned int)u) << 16; return v.f;
}

// ---------------- K0: copy f32 weights still needed as f32 ----------------
struct Prep {
  const float* s[20];
  int n[20];
  int o[20];
};
__global__ void k_prep(Prep p, float* __restrict__ ws){
  int a = blockIdx.y;
  int i = blockIdx.x * blockDim.x + threadIdx.x;
  if (i < p.n[a]) ws[p.o[a] + i] = p.s[a][i];
}

// ---------------- K0b: bf16 hi/lo splits of the MFMA weights ----------------
__global__ void k_prep2(const float* __restrict__ wenc,
                        const float* __restrict__ wihf, const float* __restrict__ wihb,
                        const float* __restrict__ whhf, const float* __restrict__ whhb,
                        const float* __restrict__ wq,   const float* __restrict__ wk,
                        const float* __restrict__ wv,   const float* __restrict__ wihc,
                        const float* __restrict__ whhc,
                        float* __restrict__ ws){
  int a = blockIdx.y;
  int i = blockIdx.x * blockDim.x + threadIdx.x;
  if (a == 0 || (a >= 5 && a <= 7)){
    if (i < 4096){
      const float* src = (a==0) ? wenc : (a==5) ? wq : (a==6) ? wk : wv;
      int oh = (a==0) ? OFF_WENCT_H : (a==5) ? OFF_WQT_H : (a==6) ? OFF_WKT_H : OFF_WVT_H;
      int ol = (a==0) ? OFF_WENCT_L : oh + 2048;
      float x = src[((i & 63) << 6) | (i >> 6)];   // T[r][c] = src[c][r]
      unsigned short h = f2bf(x);
      unsigned short l = f2bf(x - bf2f(h));
      ((unsigned short*)(ws + oh))[i] = h;
      ((unsigned short*)(ws + ol))[i] = l;
    }
  } else if (a == 1 || a == 2){
    if (i < 24576){
      float x = (a == 1 ? wihf : wihb)[i];
      unsigned short h = f2bf(x);
      unsigned short l = f2bf(x - bf2f(h));
      ((unsigned short*)(ws + (a == 1 ? OFF_WIHF_H : OFF_WIHB_H)))[i] = h;
      ((unsigned short*)(ws + (a == 1 ? OFF_WIHF_L : OFF_WIHB_L)))[i] = l;
    }
  } else if (a == 3 || a == 4){
    if (i < 12288){
      float x = (a == 3 ? whhf : whhb)[i];
      ((unsigned short*)(ws + (a == 3 ? OFF_WHHF_H : OFF_WHHB_H)))[i] = f2bf(x);
    }
  } else {
    if (i < 12288){
      float x = (a == 8 ? wihc : whhc)[i];
      unsigned short h = f2bf(x);
      unsigned short l = f2bf(x - bf2f(h));
      int oh = (a == 8 ? OFF_WIHC_H : OFF_WHHC_H);
      ((unsigned short*)(ws + oh))[i] = h;
      ((unsigned short*)(ws + oh + 6144))[i] = l;
    }
  }
}

// ---------------- K1: bidirectional 15-step GRU via bf16 MFMA ---------------
// R7: 32-node blocks.  1024 blocks x 256 thr (4 waves: lw=grp>>1, nw=grp&1).
// LDS 72KB -> 36KB => 4 blocks/CU (16 waves/CU, was 2 blk/8-wave barriers).
// Per-wave work identical to the 64-node version; only decomposition changed.
// launch_bounds(256,4): VGPR cap 128; measured use is 72 -> no spill risk.
__global__ __launch_bounds__(256, 4) void k_gru(const float* __restrict__ obs,
                                                float* __restrict__ ws){
  __shared__ float smem[9216];                // 36 KB
  float* s_u2 = smem;                         // [node32][196] : 6272 fl
  unsigned short* s_obs_h = (unsigned short*)(smem + 6272); // [32][72] hi
  unsigned short* s_obs_l = s_obs_h + 2304;                 // lo
  unsigned short* s_hbu   = (unsigned short*)(smem + 6272); // 2 x [32][88] (aliases)
  float* s_red = smem + 9088;                 // 2 x [32][2] y-partials (parity)

  const int tid = threadIdx.x;
  const int nl  = tid & 63;
  const int grp = __builtin_amdgcn_readfirstlane(tid >> 6);
  const int dir = blockIdx.x >> 9;
  const int base = (blockIdx.x & 511) * 32;
  const int lw = grp >> 1;                    // 0,1 : l-range 32*lw..+32
  const int nw = grp & 1;                     // node-tile (0,1)
  const int q  = nl >> 4;
  const int i_c = nl & 15;
  const int node = 16*nw + i_c;               // 0..31

  // P0: stage obs as bf16 hi/lo [node][72]
  {
    float4 a = *(const float4*)&obs[base*64 + tid*8];
    float4 b = *(const float4*)&obs[base*64 + tid*8 + 4];
    int nn = tid >> 3, d0 = (tid & 7)*8;
    union { v8s v; unsigned short u[8]; } H, L;
    float xs[8] = {a.x,a.y,a.z,a.w,b.x,b.y,b.z,b.w};
    #pragma unroll
    for (int e = 0; e < 8; e++){
      H.u[e] = f2bf(xs[e]);
      L.u[e] = f2bf(xs[e] - bf2f(H.u[e]));
    }
    *(v8s*)&s_obs_h[nn*72 + d0] = H.v;
    *(v8s*)&s_obs_l[nn*72 + d0] = L.v;
  }
  __syncthreads();

  // P1: h_enc = relu(obs @ Wenc + b_enc) via MFMA
  const float* benc = ws + OFF_BENC;
  const unsigned short* wtH = (const unsigned short*)(ws + OFF_WENCT_H);
  const unsigned short* wtL = (const unsigned short*)(ws + OFF_WENCT_L);
  v4f dEnc[2];
  {
    v8s obH[2], obL[2];
    #pragma unroll
    for (int kc = 0; kc < 2; kc++){
      int ba = node*72 + kc*32 + q*8;
      obH[kc] = *(const v8s*)&s_obs_h[ba];
      obL[kc] = *(const v8s*)&s_obs_l[ba];
    }
    #pragma unroll
    for (int tt = 0; tt < 2; tt++){
      int lT = 2*lw + tt;
      float4 bi = *(const float4*)&benc[16*lT + 4*q];
      v4f d = (v4f){bi.x, bi.y, bi.z, bi.w};
      #pragma unroll
      for (int kc = 0; kc < 2; kc++){
        int aa = (16*lT + i_c)*64 + kc*32 + q*8;
        v8s aH = *(const v8s*)&wtH[aa];
        v8s aL = *(const v8s*)&wtL[aa];
        d = __builtin_amdgcn_mfma_f32_16x16x32_bf16(aH, obH[kc], d, 0,0,0);
        d = __builtin_amdgcn_mfma_f32_16x16x32_bf16(aH, obL[kc], d, 0,0,0);
        d = __builtin_amdgcn_mfma_f32_16x16x32_bf16(aL, obH[kc], d, 0,0,0);
      }
      dEnc[tt] = d;
    }
  }
  __syncthreads();
  #pragma unroll
  for (int tt = 0; tt < 2; tt++){
    int lT = 2*lw + tt;
    unsigned short hh[4], ll[4];
    #pragma unroll
    for (int r = 0; r < 4; r++){
      float v = fmaxf(dEnc[tt][r], 0.0f);
      hh[r] = f2bf(v);
      ll[r] = f2bf(v - bf2f(hh[r]));
    }
    int wa = node*72 + 16*lT + 4*q;
    *(uint2*)&s_obs_h[wa] = make_uint2((unsigned)hh[0] | ((unsigned)hh[1]<<16),
                                       (unsigned)hh[2] | ((unsigned)hh[3]<<16));
    *(uint2*)&s_obs_l[wa] = make_uint2((unsigned)ll[0] | ((unsigned)ll[1]<<16),
                                       (unsigned)ll[2] | ((unsigned)ll[3]<<16));
  }
  __syncthreads();

  const float* bih = ws + (dir ? OFF_BIHB : OFF_BIHF);
  const float* bhh = ws + (dir ? OFF_BHHB : OFF_BHHF);
  const unsigned short* wiH = (const unsigned short*)(ws + (dir ? OFF_WIHB_H : OFF_WIHF_H));
  const unsigned short* wiL = (const unsigned short*)(ws + (dir ? OFF_WIHB_L : OFF_WIHF_L));
  const unsigned short* whH = (const unsigned short*)(ws + (dir ? OFF_WHHB_H : OFF_WHHF_H));

  v8s hbH[2], hbL[2];
  #pragma unroll
  for (int kc = 0; kc < 2; kc++){
    int ba = node*72 + kc*32 + q*8;
    hbH[kc] = *(const v8s*)&s_obs_h[ba];
    hbL[kc] = *(const v8s*)&s_obs_l[ba];
  }

  // P2a: u2
  #pragma unroll
  for (int m = 0; m < 6; m++){
    int T = 6*lw + m;
    v4f d = (v4f){0.f,0.f,0.f,0.f};
    #pragma unroll
    for (int kc = 0; kc < 2; kc++){
      int aa = (16*T + i_c)*128 + 64 + kc*32 + q*8;
      v8s aH = *(const v8s*)&wiH[aa];
      v8s aL = *(const v8s*)&wiL[aa];
      d = __builtin_amdgcn_mfma_f32_16x16x32_bf16(aH, hbH[kc], d, 0,0,0);
      d = __builtin_amdgcn_mfma_f32_16x16x32_bf16(aH, hbL[kc], d, 0,0,0);
      d = __builtin_amdgcn_mfma_f32_16x16x32_bf16(aL, hbH[kc], d, 0,0,0);
    }
    *(v4f*)&s_u2[node*196 + 16*T + 4*q] = d;
  }

  // P2b: cb
  v4f cbr[2], cbz[2], cbn[2], bhn4[2];
  #pragma unroll
  for (int g = 0; g < 3; g++){
    #pragma unroll
    for (int t2 = 0; t2 < 2; t2++){
      int row0 = 64*g + 32*lw + 16*t2 + 4*q;
      float4 bi = *(const float4*)&bih[row0];
      v4f d;
      if (g < 2){
        float4 bh = *(const float4*)&bhh[row0];
        d = (v4f){bi.x+bh.x, bi.y+bh.y, bi.z+bh.z, bi.w+bh.w};
      } else {
        d = (v4f){bi.x, bi.y, bi.z, bi.w};
      }
      int T = (64*g + 32*lw + 16*t2) >> 4;
      #pragma unroll
      for (int kc = 0; kc < 2; kc++){
        int aa = (16*T + i_c)*128 + kc*32 + q*8;
        v8s aH = *(const v8s*)&wiH[aa];
        v8s aL = *(const v8s*)&wiL[aa];
        d = __builtin_amdgcn_mfma_f32_16x16x32_bf16(aH, hbH[kc], d, 0,0,0);
        d = __builtin_amdgcn_mfma_f32_16x16x32_bf16(aH, hbL[kc], d, 0,0,0);
        d = __builtin_amdgcn_mfma_f32_16x16x32_bf16(aL, hbH[kc], d, 0,0,0);
      }
      if (g == 0) cbr[t2] = d; else if (g == 1) cbz[t2] = d; else cbn[t2] = d;
    }
  }
  #pragma unroll
  for (int t2 = 0; t2 < 2; t2++){
    int row0 = 128 + 32*lw + 16*t2 + 4*q;
    float4 nh = *(const float4*)&bhh[row0];
    bhn4[t2] = (v4f){nh.x, nh.y, nh.z, nh.w};
  }

  // P2c: Whh A-frags
  v8s afr[2][2], afz[2][2], afn[2][2];
  #pragma unroll
  for (int t2 = 0; t2 < 2; t2++){
    #pragma unroll
    for (int kc = 0; kc < 2; kc++){
      #pragma unroll
      for (int g = 0; g < 3; g++){
        int row = g*64 + 32*lw + 16*t2 + i_c;
        v8s a = *(const v8s*)&whH[row*64 + kc*32 + q*8];
        if (g == 0) afr[t2][kc] = a; else if (g == 1) afz[t2][kc] = a; else afn[t2][kc] = a;
      }
    }
  }

  const float* whard = ws + OFF_WHARD + dir*128;
  float wh0[8], wh1[8];
  #pragma unroll
  for (int t2 = 0; t2 < 2; t2++){
    #pragma unroll
    for (int r = 0; r < 4; r++){
      int l = 32*lw + 16*t2 + 4*q + r;
      wh0[t2*4+r] = whard[l*2];
      wh1[t2*4+r] = whard[l*2+1];
    }
  }
  __syncthreads();

  // P3: 15-step recurrence (h stride 88 ushorts; buffers 2816 ushorts apart)
  float* yout = ws + (dir ? OFF_YB : OFF_YF);

  float hv[8];
  #pragma unroll
  for (int m = 0; m < 8; m++) hv[m] = 0.0f;

  for (int kk = 0; kk < 15; kk++){
    const int t  = dir ? (14 - kk) : kk;
    const int j  = t + (t >= i_c ? 1 : 0);
    const int jl = 16*nw + j;
    const int rb = kk & 1;
    const int wb = (kk + 1) & 1;

    v8s b0, b1;
    if (kk > 0){
      const unsigned short* rp = s_hbu + rb*2816 + node*88 + q*8;
      b0 = *(const v8s*)(rp);
      b1 = *(const v8s*)(rp + 32);
    }

    float a0p = 0.f, a1p = 0.f;
    #pragma unroll
    for (int t2 = 0; t2 < 2; t2++){
      int l0 = 32*lw + 16*t2 + 4*q;
      v4f dr = cbr[t2], dz = cbz[t2];
      v4f dn = (v4f){0.f,0.f,0.f,0.f};
      if (kk > 0){
        dr = __builtin_amdgcn_mfma_f32_16x16x32_bf16(afr[t2][0], b0, dr, 0,0,0);
        dr = __builtin_amdgcn_mfma_f32_16x16x32_bf16(afr[t2][1], b1, dr, 0,0,0);
        dz = __builtin_amdgcn_mfma_f32_16x16x32_bf16(afz[t2][0], b0, dz, 0,0,0);
        dz = __builtin_amdgcn_mfma_f32_16x16x32_bf16(afz[t2][1], b1, dz, 0,0,0);
        dn = __builtin_amdgcn_mfma_f32_16x16x32_bf16(afn[t2][0], b0, dn, 0,0,0);
        dn = __builtin_amdgcn_mfma_f32_16x16x32_bf16(afn[t2][1], b1, dn, 0,0,0);
      }
      v4f ur = *(const v4f*)&s_u2[jl*196 +       l0];
      v4f uz = *(const v4f*)&s_u2[jl*196 +  64 + l0];
      v4f un = *(const v4f*)&s_u2[jl*196 + 128 + l0];
      float hn[4];
      #pragma unroll
      for (int r = 0; r < 4; r++){
        float rg = sigf(dr[r] + ur[r]);
        float zg = sigf(dz[r] + uz[r]);
        float ng = tanhfast(cbn[t2][r] + un[r] + rg*(bhn4[t2][r] + dn[r]));
        float hnew = (1.0f - zg)*ng + zg*hv[t2*4+r];
        hv[t2*4+r] = hnew;
        hn[r] = hnew;
        a0p += hnew*wh0[t2*4+r];
        a1p += hnew*wh1[t2*4+r];
      }
      unsigned int p0 = (unsigned int)f2bf(hn[0]) | ((unsigned int)f2bf(hn[1]) << 16);
      unsigned int p1 = (unsigned int)f2bf(hn[2]) | ((unsigned int)f2bf(hn[3]) << 16);
      *(uint2*)(s_hbu + wb*2816 + node*88 + l0) = make_uint2(p0, p1);
    }

    a0p += __shfl_xor(a0p, 16); a0p += __shfl_xor(a0p, 32);
    a1p += __shfl_xor(a1p, 16); a1p += __shfl_xor(a1p, 32);
    float* sr = s_red + rb*64;
    if (lw == 0 && q == 0)
      *(float2*)&sr[node*2] = make_float2(a0p, a1p);
    __syncthreads();
    if (lw == 1 && q == 0){
      float2 pp = *(const float2*)&sr[node*2];
      *(float2*)&yout[((base + node)*15 + t)*2] = make_float2(a0p + pp.x, a1p + pp.y);
    }
  }
}

// ---------------- K2: qkv + gumbel + attention + final GRU cell -------------
// R7: 32-node blocks.  512 blocks x 256 thr (4 waves).  LDS 56 -> 28.1 KB
// => up to 5 blocks/CU by LDS.  launch_bounds(256,2) leaves VGPR uncapped
// (no spill risk); occupancy set by actual VGPR/LDS use.
__global__ __launch_bounds__(256, 2) void k_attn(const float* __restrict__ obs,
                                                 const float* __restrict__ hid,
                                                 const float* __restrict__ gum,
                                                 float* __restrict__ ws,
                                                 float* __restrict__ out){
  __shared__ float smem[7200];                         // 28.1 KB
  unsigned short* s_obs_h = (unsigned short*)smem;     // [32][72] obs/h_enc hi
  unsigned short* s_obs_l = s_obs_h + 2304;            // lo
  float* s_q  = smem;                                  // [32][68] fp32 (aliases)
  unsigned short* s_h0h = (unsigned short*)smem;       // h0 hi (aliases, late)
  unsigned short* s_h0l = s_h0h + 2304;
  float* s_k  = smem + 2304;                           // [64][33]
  unsigned short* s_xh = (unsigned short*)(smem + 2304); // x frags (alias s_k, late)
  unsigned short* s_xl = s_xh + 2304;
  float* s_v  = smem + 4608;                           // [64][33]
  float* s_co = smem + 6720;                           // [15][32]

  const int tid = threadIdx.x;
  const int nl  = tid & 63;
  const int grp = __builtin_amdgcn_readfirstlane(tid >> 6);
  const int base = blockIdx.x * 32;
  const int lw = grp >> 1;
  const int nw = grp & 1;
  const int q4 = nl >> 4;
  const int i_c = nl & 15;
  const int node = 16*nw + i_c;                        // 0..31

  // P0: stage obs bf16 hi/lo [node][72]
  {
    float4 a = *(const float4*)&obs[base*64 + tid*8];
    float4 b = *(const float4*)&obs[base*64 + tid*8 + 4];
    int nn = tid >> 3, d0 = (tid & 7)*8;
    union { v8s v; unsigned short u[8]; } H, L;
    float xs[8] = {a.x,a.y,a.z,a.w,b.x,b.y,b.z,b.w};
    #pragma unroll
    for (int e = 0; e < 8; e++){
      H.u[e] = f2bf(xs[e]);
      L.u[e] = f2bf(xs[e] - bf2f(H.u[e]));
    }
    *(v8s*)&s_obs_h[nn*72 + d0] = H.v;
    *(v8s*)&s_obs_l[nn*72 + d0] = L.v;
  }
  __syncthreads();

  // P1: h_enc via MFMA
  const float* benc = ws + OFF_BENC;
  const unsigned short* wtH = (const unsigned short*)(ws + OFF_WENCT_H);
  const unsigned short* wtL = (const unsigned short*)(ws + OFF_WENCT_L);
  v4f dEnc[2];
  {
    v8s obH[2], obL[2];
    #pragma unroll
    for (int kc = 0; kc < 2; kc++){
      int ba = node*72 + kc*32 + q4*8;
      obH[kc] = *(const v8s*)&s_obs_h[ba];
      obL[kc] = *(const v8s*)&s_obs_l[ba];
    }
    #pragma unroll
    for (int tt = 0; tt < 2; tt++){
      int lT = 2*lw + tt;
      float4 bi = *(const float4*)&benc[16*lT + 4*q4];
      v4f d = (v4f){bi.x, bi.y, bi.z, bi.w};
      #pragma unroll
      for (int kc = 0; kc < 2; kc++){
        int aa = (16*lT + i_c)*64 + kc*32 + q4*8;
        v8s aH = *(const v8s*)&wtH[aa];
        v8s aL = *(const v8s*)&wtL[aa];
        d = __builtin_amdgcn_mfma_f32_16x16x32_bf16(aH, obH[kc], d, 0,0,0);
        d = __builtin_amdgcn_mfma_f32_16x16x32_bf16(aH, obL[kc], d, 0,0,0);
        d = __builtin_amdgcn_mfma_f32_16x16x32_bf16(aL, obH[kc], d, 0,0,0);
      }
      dEnc[tt] = d;
    }
  }
  __syncthreads();
  #pragma unroll
  for (int tt = 0; tt < 2; tt++){
    int lT = 2*lw + tt;
    unsigned short hh[4], ll[4];
    #pragma unroll
    for (int r = 0; r < 4; r++){
      float v = fmaxf(dEnc[tt][r], 0.0f);
      hh[r] = f2bf(v);
      ll[r] = f2bf(v - bf2f(hh[r]));
    }
    int wa = node*72 + 16*lT + 4*q4;
    *(uint2*)&s_obs_h[wa] = make_uint2((unsigned)hh[0] | ((unsigned)hh[1]<<16),
                                       (unsigned)hh[2] | ((unsigned)hh[3]<<16));
    *(uint2*)&s_obs_l[wa] = make_uint2((unsigned)ll[0] | ((unsigned)ll[1]<<16),
                                       (unsigned)ll[2] | ((unsigned)ll[3]<<16));
  }
  __syncthreads();

  // C: h_enc B-frags; q/k/v MFMA (registers only)
  v8s hbH[2], hbL[2];
  #pragma unroll
  for (int kc = 0; kc < 2; kc++){
    int ba = node*72 + kc*32 + q4*8;
    hbH[kc] = *(const v8s*)&s_obs_h[ba];
    hbL[kc] = *(const v8s*)&s_obs_l[ba];
  }
  const unsigned short* wqH = (const unsigned short*)(ws + OFF_WQT_H);
  const unsigned short* wqL = (const unsigned short*)(ws + OFF_WQT_L);
  const unsigned short* wkH = (const unsigned short*)(ws + OFF_WKT_H);
  const unsigned short* wkL = (const unsigned short*)(ws + OFF_WKT_L);
  const unsigned short* wvH = (const unsigned short*)(ws + OFF_WVT_H);
  const unsigned short* wvL = (const unsigned short*)(ws + OFF_WVT_L);
  const float* bv = ws + OFF_BV;
  v4f dq[2], dk[2], dv[2];
  #pragma unroll
  for (int a2 = 0; a2 < 2; a2++){
    int aT = 2*lw + a2;
    v4f q_ = (v4f){0.f,0.f,0.f,0.f};
    v4f k_ = (v4f){0.f,0.f,0.f,0.f};
    float4 b4 = *(const float4*)&bv[16*aT + 4*q4];
    v4f v_ = (v4f){b4.x, b4.y, b4.z, b4.w};
    #pragma unroll
    for (int kc = 0; kc < 2; kc++){
      int ai = (16*aT + i_c)*64 + kc*32 + q4*8;
      v8s aH = *(const v8s*)&wqH[ai]; v8s aL = *(const v8s*)&wqL[ai];
      q_ = __builtin_amdgcn_mfma_f32_16x16x32_bf16(aH, hbH[kc], q_, 0,0,0);
      q_ = __builtin_amdgcn_mfma_f32_16x16x32_bf16(aH, hbL[kc], q_, 0,0,0);
      q_ = __builtin_amdgcn_mfma_f32_16x16x32_bf16(aL, hbH[kc], q_, 0,0,0);
      aH = *(const v8s*)&wkH[ai]; aL = *(const v8s*)&wkL[ai];
      k_ = __builtin_amdgcn_mfma_f32_16x16x32_bf16(aH, hbH[kc], k_, 0,0,0);
      k_ = __builtin_amdgcn_mfma_f32_16x16x32_bf16(aH, hbL[kc], k_, 0,0,0);
      k_ = __builtin_amdgcn_mfma_f32_16x16x32_bf16(aL, hbH[kc], k_, 0,0,0);
      aH = *(const v8s*)&wvH[ai]; aL = *(const v8s*)&wvL[ai];
      v_ = __builtin_amdgcn_mfma_f32_16x16x32_bf16(aH, hbH[kc], v_, 0,0,0);
      v_ = __builtin_amdgcn_mfma_f32_16x16x32_bf16(aH, hbL[kc], v_, 0,0,0);
      v_ = __builtin_amdgcn_mfma_f32_16x16x32_bf16(aL, hbH[kc], v_, 0,0,0);
    }
    dq[a2] = q_; dk[a2] = k_; dv[a2] = v_;
  }
  __syncthreads();   // all s_obs frag reads done -> s_q (alias) writable

  // D: store q [node][68], k/v [a][33]
  #pragma unroll
  for (int a2 = 0; a2 < 2; a2++){
    int aT = 2*lw + a2;
    *(v4f*)&s_q[node*68 + 16*aT + 4*q4] = dq[a2];
    #pragma unroll
    for (int r = 0; r < 4; r++){
      s_k[(16*aT + 4*q4 + r)*33 + node] = dk[a2][r];
      s_v[(16*aT + 4*q4 + r)*33 + node] = fmaxf(dv[a2][r], 0.f);
    }
  }
  __syncthreads();

  // E: scores + softmax + gumbel coeffs.  Remap: n2 = node, asl = a-slice.
  const int n2  = tid >> 3;            // 0..31
  const int asl = tid & 7;
  const int ib2 = n2 & 15, jb2 = n2 & 16;
  float4 aq0 = *(const float4*)&s_q[n2*68 + asl*8];
  float4 aq1 = *(const float4*)&s_q[n2*68 + asl*8 + 4];
  float sc[15];
  #pragma unroll
  for (int t = 0; t < 15; t++){
    int jl = jb2 | (t + (t >= ib2 ? 1 : 0));
    const float* kp = s_k + (asl*8)*33 + jl;
    float s = aq0.x*kp[0]  + aq0.y*kp[33]  + aq0.z*kp[66]  + aq0.w*kp[99]
            + aq1.x*kp[132] + aq1.y*kp[165] + aq1.z*kp[198] + aq1.w*kp[231];
    s += __shfl_xor(s, 1); s += __shfl_xor(s, 2); s += __shfl_xor(s, 4);
    sc[t] = s * 0.125f;
  }
  {
    float m = sc[0];
    #pragma unroll
    for (int t = 1; t < 15; t++) m = fmaxf(m, sc[t]);
    float den = 0.f;
    #pragma unroll
    for (int t = 0; t < 15; t++) den += __expf(sc[t]-m);
    float rden = rcpf(den);
    const float bh0 = ws[OFF_BHARD], bh1 = ws[OFF_BHARD+1];
    const float* yF = ws + OFF_YF; const float* yB = ws + OFF_YB;
    #pragma unroll
    for (int t = 0; t < 15; t++){
      if ((t & 7) == asl){
        int rowb = ((base + n2)*15 + t)*2;
        float y0 = yF[rowb]   + yB[rowb]   + bh0;
        float y1 = yF[rowb+1] + yB[rowb+1] + bh1;
        float2 u2 = *(const float2*)&gum[rowb];
        float g0 = -__logf(-__logf(u2.x + EPSG) + EPSG);
        float g1 = -__logf(-__logf(u2.y + EPSG) + EPSG);
        float w  = sigf(((y1+g1) - (y0+g0)) * (1.0f/TAU_));
        s_co[t*32 + n2] = __expf(sc[t]-m)*rden*w;
      }
    }
  }
  __syncthreads();

  // F: x = sum_t coeff * v  (8 a's per thread), write x bf16 frags; stage h0
  {
    float xa[8];
    #pragma unroll
    for (int il = 0; il < 8; il++) xa[il] = 0.f;
    #pragma unroll
    for (int t = 0; t < 15; t++){
      float c = s_co[t*32 + n2];
      int jl = jb2 | (t + (t >= ib2 ? 1 : 0));
      const float* vp = s_v + (asl*8)*33 + jl;
      xa[0] += c*vp[0];    xa[1] += c*vp[33];   xa[2] += c*vp[66];   xa[3] += c*vp[99];
      xa[4] += c*vp[132];  xa[5] += c*vp[165];  xa[6] += c*vp[198];  xa[7] += c*vp[231];
    }
    union { v8s v; unsigned short u[8]; } XH, XL;
    #pragma unroll
    for (int e = 0; e < 8; e++){
      XH.u[e] = f2bf(xa[e]);
      XL.u[e] = f2bf(xa[e] - bf2f(XH.u[e]));
    }
    *(v8s*)&s_xh[n2*72 + asl*8] = XH.v;
    *(v8s*)&s_xl[n2*72 + asl*8] = XL.v;
  }
  {
    float4 a = *(const float4*)&hid[base*64 + tid*8];
    float4 b = *(const float4*)&hid[base*64 + tid*8 + 4];
    int nn = tid >> 3, d0 = (tid & 7)*8;
    union { v8s v; unsigned short u[8]; } H, L;
    float xs[8] = {a.x,a.y,a.z,a.w,b.x,b.y,b.z,b.w};
    #pragma unroll
    for (int e = 0; e < 8; e++){
      H.u[e] = f2bf(xs[e]);
      L.u[e] = f2bf(xs[e] - bf2f(H.u[e]));
    }
    *(v8s*)&s_h0h[nn*72 + d0] = H.v;
    *(v8s*)&s_h0l[nn*72 + d0] = L.v;
  }
  __syncthreads();

  // G: final GRU cell via MFMA: gi = Wihc.x, gh = Whhc.h0
  v8s xbH[2], xbL[2], h0H[2], h0L[2];
  #pragma unroll
  for (int kc = 0; kc < 2; kc++){
    int ba = node*72 + kc*32 + q4*8;
    xbH[kc] = *(const v8s*)&s_xh[ba];  xbL[kc] = *(const v8s*)&s_xl[ba];
    h0H[kc] = *(const v8s*)&s_h0h[ba]; h0L[kc] = *(const v8s*)&s_h0l[ba];
  }
  const unsigned short* wiH = (const unsigned short*)(ws + OFF_WIHC_H);
  const unsigned short* wiL = (const unsigned short*)(ws + OFF_WIHC_L);
  const unsigned short* whH = (const unsigned short*)(ws + OFF_WHHC_H);
  const unsigned short* whL = (const unsigned short*)(ws + OFF_WHHC_L);
  const float* bihc = ws + OFF_BIHC; const float* bhhc = ws + OFF_BHHC;
  v4f gi[3][2], gh[3][2];
  #pragma unroll
  for (int g = 0; g < 3; g++){
    #pragma unroll
    for (int u2 = 0; u2 < 2; u2++){
      int u = 2*lw + u2;
      int row0 = g*64 + 16*u + 4*q4;
      float4 bi = *(const float4*)&bihc[row0];
      float4 bh = *(const float4*)&bhhc[row0];
      v4f di, dh;
      if (g < 2){
        di = (v4f){bi.x+bh.x, bi.y+bh.y, bi.z+bh.z, bi.w+bh.w};
        dh = (v4f){0.f,0.f,0.f,0.f};
      } else {
        di = (v4f){bi.x, bi.y, bi.z, bi.w};
        dh = (v4f){bh.x, bh.y, bh.z, bh.w};
      }
      #pragma unroll
      for (int kc = 0; kc < 2; kc++){
        int ai = (g*64 + 16*u + i_c)*64 + kc*32 + q4*8;
        v8s aH = *(const v8s*)&wiH[ai]; v8s aL = *(const v8s*)&wiL[ai];
        di = __builtin_amdgcn_mfma_f32_16x16x32_bf16(aH, xbH[kc], di, 0,0,0);
        di = __builtin_amdgcn_mfma_f32_16x16x32_bf16(aH, xbL[kc], di, 0,0,0);
        di = __builtin_amdgcn_mfma_f32_16x16x32_bf16(aL, xbH[kc], di, 0,0,0);
        aH = *(const v8s*)&whH[ai]; aL = *(const v8s*)&whL[ai];
        dh = __builtin_amdgcn_mfma_f32_16x16x32_bf16(aH, h0H[kc], dh, 0,0,0);
        dh = __builtin_amdgcn_mfma_f32_16x16x32_bf16(aH, h0L[kc], dh, 0,0,0);
        dh = __builtin_amdgcn_mfma_f32_16x16x32_bf16(aL, h0H[kc], dh, 0,0,0);
      }
      gi[g][u2] = di; gh[g][u2] = dh;
    }
  }
  #pragma unroll
  for (int u2 = 0; u2 < 2; u2++){
    int l0 = 16*(2*lw + u2) + 4*q4;
    float4 h04 = *(const float4*)&hid[(base+node)*64 + l0];
    float hh[4] = {h04.x, h04.y, h04.z, h04.w};
    float ho[4];
    #pragma unroll
    for (int r = 0; r < 4; r++){
      float rg = sigf(gi[0][u2][r] + gh[0][u2][r]);
      float zg = sigf(gi[1][u2][r] + gh[1][u2][r]);
      float ng = tanhfast(gi[2][u2][r] + rg*gh[2][u2][r]);
      ho[r] = (1.0f - zg)*ng + zg*hh[r];
    }
    *(float4*)&out[(base+node)*64 + l0] = make_float4(ho[0], ho[1], ho[2], ho[3]);
  }
}

extern "C" void kernel_launch(void* const* d_in, const int* in_sizes, int n_in,
                              void* d_out, int out_size, void* d_ws, size_t ws_size,
                              hipStream_t stream){
  if (ws_size < (size_t)WS_FLOATS * sizeof(float)) return;
  float* ws = (float*)d_ws;
  // f32 copies still needed; MFMA weights go through k_prep2 bf16 splits
  static const int offs[20] = {OFF_WENC, OFF_BENC, 0, 0, OFF_BIHF, OFF_BHHF,
      0, 0, OFF_BIHB, OFF_BHHB, OFF_WHARD, OFF_BHARD, 0, 0, 0,
      OFF_BV, 0, 0, OFF_BIHC, OFF_BHHC};
  Prep p;
  for (int i = 0; i < 20; i++){
    p.s[i] = (const float*)d_in[3 + i];
    p.n[i] = in_sizes[3 + i];
    p.o[i] = offs[i];
  }
  // zero out f32 copies replaced by bf16 splits:
  p.n[2] = 0; p.n[3] = 0; p.n[6] = 0; p.n[7] = 0;      // Wih_f/Whh_f/Wih_b/Whh_b
  p.n[12] = 0; p.n[13] = 0; p.n[14] = 0;               // Wq/Wk/Wv
  p.n[16] = 0; p.n[17] = 0;                            // Wih_c/Whh_c
  hipLaunchKernelGGL(k_prep, dim3(96, 20), dim3(256), 0, stream, p, ws);
  hipLaunchKernelGGL(k_prep2, dim3(96, 10), dim3(256), 0, stream,
                     (const float*)d_in[3], (const float*)d_in[5], (const float*)d_in[9],
                     (const float*)d_in[6], (const float*)d_in[10],
                     (const float*)d_in[15], (const float*)d_in[16], (const float*)d_in[17],
                     (const float*)d_in[19], (const float*)d_in[20], ws);
  hipLaunchKernelGGL(k_gru,  dim3(1024),   dim3(256), 0, stream,
                     (const float*)d_in[0], ws);
  hipLaunchKernelGGL(k_attn, dim3(512),    dim3(256), 0, stream,
                     (const float*)d_in[0], (const float*)d_in[1],
                     (const float*)d_in[2], ws, (float*)d_out);
}

// Round 8
// 187.758 us; speedup vs baseline: 1.1023x; 1.1023x over previous
//
#include <hip/hip_runtime.h>
#include <hip/hip_bf16.h>
#include <stdint.h>

// B=1024, N=16, D=64, H=64, A=64 -> 16384 nodes. All tensors fp32.
#define NNODE 16384
#define TAU_ 0.01f
#define EPSG 1e-10f

// ---- workspace layout (float offsets); total 1,114,112 floats = 4.25 MB ----
#define OFF_WENC 0
#define OFF_BENC 4096
#define OFF_WIHF_H 4160      // 192x128 bf16 = 24576 ushort = 12288 fl
#define OFF_WIHF_L 16448
#define OFF_WHHF_H 28736     // 192x64 bf16 hi
#define OFF_BIHF 41024
#define OFF_BHHF 41216
#define OFF_WIHB_H 41408
#define OFF_WIHB_L 53696
#define OFF_WHHB_H 65984
#define OFF_BIHB 78272
#define OFF_BHHB 78464
#define OFF_WHARD 78656
#define OFF_BHARD 78912
// bf16 hi/lo splits for k_attn MFMA (reuse old f32 Wq/Wk/Wv/Wihc/Whhc slots)
#define OFF_WQT_H 78914      // Wq^T 64x64: 4096 ushort = 2048 fl
#define OFF_WQT_L 80962
#define OFF_WKT_H 83010
#define OFF_WKT_L 85058
#define OFF_WVT_H 87106
#define OFF_WVT_L 89154
#define OFF_BV 91202
#define OFF_WIHC_H 91266     // 192x64: 12288 ushort = 6144 fl
#define OFF_WIHC_L 97410
#define OFF_WHHC_H 103554
#define OFF_WHHC_L 109698
#define OFF_BIHC 115842
#define OFF_BHHC 116034
#define OFF_WENCT_H 118784   // Wenc^T bf16 hi: 64x64
#define OFF_WENCT_L 120832
#define OFF_YF 131072
#define OFF_YB (OFF_YF + 491520)
#define WS_FLOATS (OFF_YB + 491520)

typedef float  v4f __attribute__((ext_vector_type(4)));
typedef short  v8s __attribute__((ext_vector_type(8)));

// v_rcp_f32 (1-ulp approx) instead of precise fp32 division (R6: -31 us).
__device__ __forceinline__ float rcpf(float x){ return __builtin_amdgcn_rcpf(x); }
__device__ __forceinline__ float sigf(float x){ return rcpf(1.0f + __expf(-x)); }
__device__ __forceinline__ float tanhfast(float x){ return 1.0f - 2.0f*rcpf(__expf(2.0f*x)+1.0f); }
__device__ __forceinline__ unsigned short f2bf(float f){
  __hip_bfloat16 h = __float2bfloat16(f);
  return *reinterpret_cast<unsigned short*>(&h);
}
__device__ __forceinline__ float bf2f(unsigned short u){
  union { unsigned int i; float f; } v; v.i = ((unsigned int)u) << 16; return v.f;
}

// ---------------- K0: copy f32 weights still needed as f32 ----------------
struct Prep {
  const float* s[20];
  int n[20];
  int o[20];
};
__global__ void k_prep(Prep p, float* __restrict__ ws){
  int a = blockIdx.y;
  int i = blockIdx.x * blockDim.x + threadIdx.x;
  if (i < p.n[a]) ws[p.o[a] + i] = p.s[a][i];
}

// ---------------- K0b: bf16 hi/lo splits of the MFMA weights ----------------
__global__ void k_prep2(const float* __restrict__ wenc,
                        const float* __restrict__ wihf, const float* __restrict__ wihb,
                        const float* __restrict__ whhf, const float* __restrict__ whhb,
                        const float* __restrict__ wq,   const float* __restrict__ wk,
                        const float* __restrict__ wv,   const float* __restrict__ wihc,
                        const float* __restrict__ whhc,
                        float* __restrict__ ws){
  int a = blockIdx.y;
  int i = blockIdx.x * blockDim.x + threadIdx.x;
  if (a == 0 || (a >= 5 && a <= 7)){
    if (i < 4096){
      const float* src = (a==0) ? wenc : (a==5) ? wq : (a==6) ? wk : wv;
      int oh = (a==0) ? OFF_WENCT_H : (a==5) ? OFF_WQT_H : (a==6) ? OFF_WKT_H : OFF_WVT_H;
      int ol = (a==0) ? OFF_WENCT_L : oh + 2048;
      float x = src[((i & 63) << 6) | (i >> 6)];   // T[r][c] = src[c][r]
      unsigned short h = f2bf(x);
      unsigned short l = f2bf(x - bf2f(h));
      ((unsigned short*)(ws + oh))[i] = h;
      ((unsigned short*)(ws + ol))[i] = l;
    }
  } else if (a == 1 || a == 2){
    if (i < 24576){
      float x = (a == 1 ? wihf : wihb)[i];
      unsigned short h = f2bf(x);
      unsigned short l = f2bf(x - bf2f(h));
      ((unsigned short*)(ws + (a == 1 ? OFF_WIHF_H : OFF_WIHB_H)))[i] = h;
      ((unsigned short*)(ws + (a == 1 ? OFF_WIHF_L : OFF_WIHB_L)))[i] = l;
    }
  } else if (a == 3 || a == 4){
    if (i < 12288){
      float x = (a == 3 ? whhf : whhb)[i];
      ((unsigned short*)(ws + (a == 3 ? OFF_WHHF_H : OFF_WHHB_H)))[i] = f2bf(x);
    }
  } else {
    if (i < 12288){
      float x = (a == 8 ? wihc : whhc)[i];
      unsigned short h = f2bf(x);
      unsigned short l = f2bf(x - bf2f(h));
      int oh = (a == 8 ? OFF_WIHC_H : OFF_WHHC_H);
      ((unsigned short*)(ws + oh))[i] = h;
      ((unsigned short*)(ws + oh + 6144))[i] = l;
    }
  }
}

// ---------------- K1: bidirectional 15-step GRU via bf16 MFMA ---------------
// 32-node blocks: 1024 blocks x 256 thr (4 waves: lw=grp>>1, nw=grp&1).
// LDS 36KB => 4 blocks/CU (16 waves/CU).
// launch_bounds EMPIRICAL RULE (R1/R2/R7): VGPR cap = 256/arg2 (waves/EU =
// 2*arg2, indep. of block size).  R7's (256,4) -> cap 64 -> 35MB spill.
// (256,2) -> cap 128; actual need ~72-100 -> no spill; LDS still the
// occupancy limiter at 4 blocks/CU.
__global__ __launch_bounds__(256, 2) void k_gru(const float* __restrict__ obs,
                                                float* __restrict__ ws){
  __shared__ float smem[9216];                // 36 KB
  float* s_u2 = smem;                         // [node32][196] : 6272 fl
  unsigned short* s_obs_h = (unsigned short*)(smem + 6272); // [32][72] hi
  unsigned short* s_obs_l = s_obs_h + 2304;                 // lo
  unsigned short* s_hbu   = (unsigned short*)(smem + 6272); // 2 x [32][88] (aliases)
  float* s_red = smem + 9088;                 // 2 x [32][2] y-partials (parity)

  const int tid = threadIdx.x;
  const int nl  = tid & 63;
  const int grp = __builtin_amdgcn_readfirstlane(tid >> 6);
  const int dir = blockIdx.x >> 9;
  const int base = (blockIdx.x & 511) * 32;
  const int lw = grp >> 1;                    // 0,1 : l-range 32*lw..+32
  const int nw = grp & 1;                     // node-tile (0,1)
  const int q  = nl >> 4;
  const int i_c = nl & 15;
  const int node = 16*nw + i_c;               // 0..31

  // P0: stage obs as bf16 hi/lo [node][72]
  {
    float4 a = *(const float4*)&obs[base*64 + tid*8];
    float4 b = *(const float4*)&obs[base*64 + tid*8 + 4];
    int nn = tid >> 3, d0 = (tid & 7)*8;
    union { v8s v; unsigned short u[8]; } H, L;
    float xs[8] = {a.x,a.y,a.z,a.w,b.x,b.y,b.z,b.w};
    #pragma unroll
    for (int e = 0; e < 8; e++){
      H.u[e] = f2bf(xs[e]);
      L.u[e] = f2bf(xs[e] - bf2f(H.u[e]));
    }
    *(v8s*)&s_obs_h[nn*72 + d0] = H.v;
    *(v8s*)&s_obs_l[nn*72 + d0] = L.v;
  }
  __syncthreads();

  // P1: h_enc = relu(obs @ Wenc + b_enc) via MFMA
  const float* benc = ws + OFF_BENC;
  const unsigned short* wtH = (const unsigned short*)(ws + OFF_WENCT_H);
  const unsigned short* wtL = (const unsigned short*)(ws + OFF_WENCT_L);
  v4f dEnc[2];
  {
    v8s obH[2], obL[2];
    #pragma unroll
    for (int kc = 0; kc < 2; kc++){
      int ba = node*72 + kc*32 + q*8;
      obH[kc] = *(const v8s*)&s_obs_h[ba];
      obL[kc] = *(const v8s*)&s_obs_l[ba];
    }
    #pragma unroll
    for (int tt = 0; tt < 2; tt++){
      int lT = 2*lw + tt;
      float4 bi = *(const float4*)&benc[16*lT + 4*q];
      v4f d = (v4f){bi.x, bi.y, bi.z, bi.w};
      #pragma unroll
      for (int kc = 0; kc < 2; kc++){
        int aa = (16*lT + i_c)*64 + kc*32 + q*8;
        v8s aH = *(const v8s*)&wtH[aa];
        v8s aL = *(const v8s*)&wtL[aa];
        d = __builtin_amdgcn_mfma_f32_16x16x32_bf16(aH, obH[kc], d, 0,0,0);
        d = __builtin_amdgcn_mfma_f32_16x16x32_bf16(aH, obL[kc], d, 0,0,0);
        d = __builtin_amdgcn_mfma_f32_16x16x32_bf16(aL, obH[kc], d, 0,0,0);
      }
      dEnc[tt] = d;
    }
  }
  __syncthreads();
  #pragma unroll
  for (int tt = 0; tt < 2; tt++){
    int lT = 2*lw + tt;
    unsigned short hh[4], ll[4];
    #pragma unroll
    for (int r = 0; r < 4; r++){
      float v = fmaxf(dEnc[tt][r], 0.0f);
      hh[r] = f2bf(v);
      ll[r] = f2bf(v - bf2f(hh[r]));
    }
    int wa = node*72 + 16*lT + 4*q;
    *(uint2*)&s_obs_h[wa] = make_uint2((unsigned)hh[0] | ((unsigned)hh[1]<<16),
                                       (unsigned)hh[2] | ((unsigned)hh[3]<<16));
    *(uint2*)&s_obs_l[wa] = make_uint2((unsigned)ll[0] | ((unsigned)ll[1]<<16),
                                       (unsigned)ll[2] | ((unsigned)ll[3]<<16));
  }
  __syncthreads();

  const float* bih = ws + (dir ? OFF_BIHB : OFF_BIHF);
  const float* bhh = ws + (dir ? OFF_BHHB : OFF_BHHF);
  const unsigned short* wiH = (const unsigned short*)(ws + (dir ? OFF_WIHB_H : OFF_WIHF_H));
  const unsigned short* wiL = (const unsigned short*)(ws + (dir ? OFF_WIHB_L : OFF_WIHF_L));
  const unsigned short* whH = (const unsigned short*)(ws + (dir ? OFF_WHHB_H : OFF_WHHF_H));

  v8s hbH[2], hbL[2];
  #pragma unroll
  for (int kc = 0; kc < 2; kc++){
    int ba = node*72 + kc*32 + q*8;
    hbH[kc] = *(const v8s*)&s_obs_h[ba];
    hbL[kc] = *(const v8s*)&s_obs_l[ba];
  }

  // P2a: u2
  #pragma unroll
  for (int m = 0; m < 6; m++){
    int T = 6*lw + m;
    v4f d = (v4f){0.f,0.f,0.f,0.f};
    #pragma unroll
    for (int kc = 0; kc < 2; kc++){
      int aa = (16*T + i_c)*128 + 64 + kc*32 + q*8;
      v8s aH = *(const v8s*)&wiH[aa];
      v8s aL = *(const v8s*)&wiL[aa];
      d = __builtin_amdgcn_mfma_f32_16x16x32_bf16(aH, hbH[kc], d, 0,0,0);
      d = __builtin_amdgcn_mfma_f32_16x16x32_bf16(aH, hbL[kc], d, 0,0,0);
      d = __builtin_amdgcn_mfma_f32_16x16x32_bf16(aL, hbH[kc], d, 0,0,0);
    }
    *(v4f*)&s_u2[node*196 + 16*T + 4*q] = d;
  }

  // P2b: cb
  v4f cbr[2], cbz[2], cbn[2], bhn4[2];
  #pragma unroll
  for (int g = 0; g < 3; g++){
    #pragma unroll
    for (int t2 = 0; t2 < 2; t2++){
      int row0 = 64*g + 32*lw + 16*t2 + 4*q;
      float4 bi = *(const float4*)&bih[row0];
      v4f d;
      if (g < 2){
        float4 bh = *(const float4*)&bhh[row0];
        d = (v4f){bi.x+bh.x, bi.y+bh.y, bi.z+bh.z, bi.w+bh.w};
      } else {
        d = (v4f){bi.x, bi.y, bi.z, bi.w};
      }
      int T = (64*g + 32*lw + 16*t2) >> 4;
      #pragma unroll
      for (int kc = 0; kc < 2; kc++){
        int aa = (16*T + i_c)*128 + kc*32 + q*8;
        v8s aH = *(const v8s*)&wiH[aa];
        v8s aL = *(const v8s*)&wiL[aa];
        d = __builtin_amdgcn_mfma_f32_16x16x32_bf16(aH, hbH[kc], d, 0,0,0);
        d = __builtin_amdgcn_mfma_f32_16x16x32_bf16(aH, hbL[kc], d, 0,0,0);
        d = __builtin_amdgcn_mfma_f32_16x16x32_bf16(aL, hbH[kc], d, 0,0,0);
      }
      if (g == 0) cbr[t2] = d; else if (g == 1) cbz[t2] = d; else cbn[t2] = d;
    }
  }
  #pragma unroll
  for (int t2 = 0; t2 < 2; t2++){
    int row0 = 128 + 32*lw + 16*t2 + 4*q;
    float4 nh = *(const float4*)&bhh[row0];
    bhn4[t2] = (v4f){nh.x, nh.y, nh.z, nh.w};
  }

  // P2c: Whh A-frags
  v8s afr[2][2], afz[2][2], afn[2][2];
  #pragma unroll
  for (int t2 = 0; t2 < 2; t2++){
    #pragma unroll
    for (int kc = 0; kc < 2; kc++){
      #pragma unroll
      for (int g = 0; g < 3; g++){
        int row = g*64 + 32*lw + 16*t2 + i_c;
        v8s a = *(const v8s*)&whH[row*64 + kc*32 + q*8];
        if (g == 0) afr[t2][kc] = a; else if (g == 1) afz[t2][kc] = a; else afn[t2][kc] = a;
      }
    }
  }

  const float* whard = ws + OFF_WHARD + dir*128;
  float wh0[8], wh1[8];
  #pragma unroll
  for (int t2 = 0; t2 < 2; t2++){
    #pragma unroll
    for (int r = 0; r < 4; r++){
      int l = 32*lw + 16*t2 + 4*q + r;
      wh0[t2*4+r] = whard[l*2];
      wh1[t2*4+r] = whard[l*2+1];
    }
  }
  __syncthreads();

  // P3: 15-step recurrence (h stride 88 ushorts; buffers 2816 ushorts apart)
  float* yout = ws + (dir ? OFF_YB : OFF_YF);

  float hv[8];
  #pragma unroll
  for (int m = 0; m < 8; m++) hv[m] = 0.0f;

  for (int kk = 0; kk < 15; kk++){
    const int t  = dir ? (14 - kk) : kk;
    const int j  = t + (t >= i_c ? 1 : 0);
    const int jl = 16*nw + j;
    const int rb = kk & 1;
    const int wb = (kk + 1) & 1;

    v8s b0, b1;
    if (kk > 0){
      const unsigned short* rp = s_hbu + rb*2816 + node*88 + q*8;
      b0 = *(const v8s*)(rp);
      b1 = *(const v8s*)(rp + 32);
    }

    float a0p = 0.f, a1p = 0.f;
    #pragma unroll
    for (int t2 = 0; t2 < 2; t2++){
      int l0 = 32*lw + 16*t2 + 4*q;
      v4f dr = cbr[t2], dz = cbz[t2];
      v4f dn = (v4f){0.f,0.f,0.f,0.f};
      if (kk > 0){
        dr = __builtin_amdgcn_mfma_f32_16x16x32_bf16(afr[t2][0], b0, dr, 0,0,0);
        dr = __builtin_amdgcn_mfma_f32_16x16x32_bf16(afr[t2][1], b1, dr, 0,0,0);
        dz = __builtin_amdgcn_mfma_f32_16x16x32_bf16(afz[t2][0], b0, dz, 0,0,0);
        dz = __builtin_amdgcn_mfma_f32_16x16x32_bf16(afz[t2][1], b1, dz, 0,0,0);
        dn = __builtin_amdgcn_mfma_f32_16x16x32_bf16(afn[t2][0], b0, dn, 0,0,0);
        dn = __builtin_amdgcn_mfma_f32_16x16x32_bf16(afn[t2][1], b1, dn, 0,0,0);
      }
      v4f ur = *(const v4f*)&s_u2[jl*196 +       l0];
      v4f uz = *(const v4f*)&s_u2[jl*196 +  64 + l0];
      v4f un = *(const v4f*)&s_u2[jl*196 + 128 + l0];
      float hn[4];
      #pragma unroll
      for (int r = 0; r < 4; r++){
        float rg = sigf(dr[r] + ur[r]);
        float zg = sigf(dz[r] + uz[r]);
        float ng = tanhfast(cbn[t2][r] + un[r] + rg*(bhn4[t2][r] + dn[r]));
        float hnew = (1.0f - zg)*ng + zg*hv[t2*4+r];
        hv[t2*4+r] = hnew;
        hn[r] = hnew;
        a0p += hnew*wh0[t2*4+r];
        a1p += hnew*wh1[t2*4+r];
      }
      unsigned int p0 = (unsigned int)f2bf(hn[0]) | ((unsigned int)f2bf(hn[1]) << 16);
      unsigned int p1 = (unsigned int)f2bf(hn[2]) | ((unsigned int)f2bf(hn[3]) << 16);
      *(uint2*)(s_hbu + wb*2816 + node*88 + l0) = make_uint2(p0, p1);
    }

    a0p += __shfl_xor(a0p, 16); a0p += __shfl_xor(a0p, 32);
    a1p += __shfl_xor(a1p, 16); a1p += __shfl_xor(a1p, 32);
    float* sr = s_red + rb*64;
    if (lw == 0 && q == 0)
      *(float2*)&sr[node*2] = make_float2(a0p, a1p);
    __syncthreads();
    if (lw == 1 && q == 0){
      float2 pp = *(const float2*)&sr[node*2];
      *(float2*)&yout[((base + node)*15 + t)*2] = make_float2(a0p + pp.x, a1p + pp.y);
    }
  }
}

// ---------------- K2: qkv + gumbel + attention + final GRU cell -------------
// 32-node blocks: 512 blocks x 256 thr (4 waves).  LDS 28.1 KB.
// launch_bounds(256,1): VGPR cap 256 under the empirical 256/arg2 rule --
// R7's (256,2) capped at 128 which may have been marginal for the ~128-VGPR
// body; arg2=1 removes any cap pressure (allocator stays lean on its own).
__global__ __launch_bounds__(256, 1) void k_attn(const float* __restrict__ obs,
                                                 const float* __restrict__ hid,
                                                 const float* __restrict__ gum,
                                                 float* __restrict__ ws,
                                                 float* __restrict__ out){
  __shared__ float smem[7200];                         // 28.1 KB
  unsigned short* s_obs_h = (unsigned short*)smem;     // [32][72] obs/h_enc hi
  unsigned short* s_obs_l = s_obs_h + 2304;            // lo
  float* s_q  = smem;                                  // [32][68] fp32 (aliases)
  unsigned short* s_h0h = (unsigned short*)smem;       // h0 hi (aliases, late)
  unsigned short* s_h0l = s_h0h + 2304;
  float* s_k  = smem + 2304;                           // [64][33]
  unsigned short* s_xh = (unsigned short*)(smem + 2304); // x frags (alias s_k, late)
  unsigned short* s_xl = s_xh + 2304;
  float* s_v  = smem + 4608;                           // [64][33]
  float* s_co = smem + 6720;                           // [15][32]

  const int tid = threadIdx.x;
  const int nl  = tid & 63;
  const int grp = __builtin_amdgcn_readfirstlane(tid >> 6);
  const int base = blockIdx.x * 32;
  const int lw = grp >> 1;
  const int nw = grp & 1;
  const int q4 = nl >> 4;
  const int i_c = nl & 15;
  const int node = 16*nw + i_c;                        // 0..31

  // P0: stage obs bf16 hi/lo [node][72]
  {
    float4 a = *(const float4*)&obs[base*64 + tid*8];
    float4 b = *(const float4*)&obs[base*64 + tid*8 + 4];
    int nn = tid >> 3, d0 = (tid & 7)*8;
    union { v8s v; unsigned short u[8]; } H, L;
    float xs[8] = {a.x,a.y,a.z,a.w,b.x,b.y,b.z,b.w};
    #pragma unroll
    for (int e = 0; e < 8; e++){
      H.u[e] = f2bf(xs[e]);
      L.u[e] = f2bf(xs[e] - bf2f(H.u[e]));
    }
    *(v8s*)&s_obs_h[nn*72 + d0] = H.v;
    *(v8s*)&s_obs_l[nn*72 + d0] = L.v;
  }
  __syncthreads();

  // P1: h_enc via MFMA
  const float* benc = ws + OFF_BENC;
  const unsigned short* wtH = (const unsigned short*)(ws + OFF_WENCT_H);
  const unsigned short* wtL = (const unsigned short*)(ws + OFF_WENCT_L);
  v4f dEnc[2];
  {
    v8s obH[2], obL[2];
    #pragma unroll
    for (int kc = 0; kc < 2; kc++){
      int ba = node*72 + kc*32 + q4*8;
      obH[kc] = *(const v8s*)&s_obs_h[ba];
      obL[kc] = *(const v8s*)&s_obs_l[ba];
    }
    #pragma unroll
    for (int tt = 0; tt < 2; tt++){
      int lT = 2*lw + tt;
      float4 bi = *(const float4*)&benc[16*lT + 4*q4];
      v4f d = (v4f){bi.x, bi.y, bi.z, bi.w};
      #pragma unroll
      for (int kc = 0; kc < 2; kc++){
        int aa = (16*lT + i_c)*64 + kc*32 + q4*8;
        v8s aH = *(const v8s*)&wtH[aa];
        v8s aL = *(const v8s*)&wtL[aa];
        d = __builtin_amdgcn_mfma_f32_16x16x32_bf16(aH, obH[kc], d, 0,0,0);
        d = __builtin_amdgcn_mfma_f32_16x16x32_bf16(aH, obL[kc], d, 0,0,0);
        d = __builtin_amdgcn_mfma_f32_16x16x32_bf16(aL, obH[kc], d, 0,0,0);
      }
      dEnc[tt] = d;
    }
  }
  __syncthreads();
  #pragma unroll
  for (int tt = 0; tt < 2; tt++){
    int lT = 2*lw + tt;
    unsigned short hh[4], ll[4];
    #pragma unroll
    for (int r = 0; r < 4; r++){
      float v = fmaxf(dEnc[tt][r], 0.0f);
      hh[r] = f2bf(v);
      ll[r] = f2bf(v - bf2f(hh[r]));
    }
    int wa = node*72 + 16*lT + 4*q4;
    *(uint2*)&s_obs_h[wa] = make_uint2((unsigned)hh[0] | ((unsigned)hh[1]<<16),
                                       (unsigned)hh[2] | ((unsigned)hh[3]<<16));
    *(uint2*)&s_obs_l[wa] = make_uint2((unsigned)ll[0] | ((unsigned)ll[1]<<16),
                                       (unsigned)ll[2] | ((unsigned)ll[3]<<16));
  }
  __syncthreads();

  // C: h_enc B-frags; q/k/v MFMA (registers only)
  v8s hbH[2], hbL[2];
  #pragma unroll
  for (int kc = 0; kc < 2; kc++){
    int ba = node*72 + kc*32 + q4*8;
    hbH[kc] = *(const v8s*)&s_obs_h[ba];
    hbL[kc] = *(const v8s*)&s_obs_l[ba];
  }
  const unsigned short* wqH = (const unsigned short*)(ws + OFF_WQT_H);
  const unsigned short* wqL = (const unsigned short*)(ws + OFF_WQT_L);
  const unsigned short* wkH = (const unsigned short*)(ws + OFF_WKT_H);
  const unsigned short* wkL = (const unsigned short*)(ws + OFF_WKT_L);
  const unsigned short* wvH = (const unsigned short*)(ws + OFF_WVT_H);
  const unsigned short* wvL = (const unsigned short*)(ws + OFF_WVT_L);
  const float* bv = ws + OFF_BV;
  v4f dq[2], dk[2], dv[2];
  #pragma unroll
  for (int a2 = 0; a2 < 2; a2++){
    int aT = 2*lw + a2;
    v4f q_ = (v4f){0.f,0.f,0.f,0.f};
    v4f k_ = (v4f){0.f,0.f,0.f,0.f};
    float4 b4 = *(const float4*)&bv[16*aT + 4*q4];
    v4f v_ = (v4f){b4.x, b4.y, b4.z, b4.w};
    #pragma unroll
    for (int kc = 0; kc < 2; kc++){
      int ai = (16*aT + i_c)*64 + kc*32 + q4*8;
      v8s aH = *(const v8s*)&wqH[ai]; v8s aL = *(const v8s*)&wqL[ai];
      q_ = __builtin_amdgcn_mfma_f32_16x16x32_bf16(aH, hbH[kc], q_, 0,0,0);
      q_ = __builtin_amdgcn_mfma_f32_16x16x32_bf16(aH, hbL[kc], q_, 0,0,0);
      q_ = __builtin_amdgcn_mfma_f32_16x16x32_bf16(aL, hbH[kc], q_, 0,0,0);
      aH = *(const v8s*)&wkH[ai]; aL = *(const v8s*)&wkL[ai];
      k_ = __builtin_amdgcn_mfma_f32_16x16x32_bf16(aH, hbH[kc], k_, 0,0,0);
      k_ = __builtin_amdgcn_mfma_f32_16x16x32_bf16(aH, hbL[kc], k_, 0,0,0);
      k_ = __builtin_amdgcn_mfma_f32_16x16x32_bf16(aL, hbH[kc], k_, 0,0,0);
      aH = *(const v8s*)&wvH[ai]; aL = *(const v8s*)&wvL[ai];
      v_ = __builtin_amdgcn_mfma_f32_16x16x32_bf16(aH, hbH[kc], v_, 0,0,0);
      v_ = __builtin_amdgcn_mfma_f32_16x16x32_bf16(aH, hbL[kc], v_, 0,0,0);
      v_ = __builtin_amdgcn_mfma_f32_16x16x32_bf16(aL, hbH[kc], v_, 0,0,0);
    }
    dq[a2] = q_; dk[a2] = k_; dv[a2] = v_;
  }
  __syncthreads();   // all s_obs frag reads done -> s_q (alias) writable

  // D: store q [node][68], k/v [a][33]
  #pragma unroll
  for (int a2 = 0; a2 < 2; a2++){
    int aT = 2*lw + a2;
    *(v4f*)&s_q[node*68 + 16*aT + 4*q4] = dq[a2];
    #pragma unroll
    for (int r = 0; r < 4; r++){
      s_k[(16*aT + 4*q4 + r)*33 + node] = dk[a2][r];
      s_v[(16*aT + 4*q4 + r)*33 + node] = fmaxf(dv[a2][r], 0.f);
    }
  }
  __syncthreads();

  // E: scores + softmax + gumbel coeffs.  Remap: n2 = node, asl = a-slice.
  const int n2  = tid >> 3;            // 0..31
  const int asl = tid & 7;
  const int ib2 = n2 & 15, jb2 = n2 & 16;
  float4 aq0 = *(const float4*)&s_q[n2*68 + asl*8];
  float4 aq1 = *(const float4*)&s_q[n2*68 + asl*8 + 4];
  float sc[15];
  #pragma unroll
  for (int t = 0; t < 15; t++){
    int jl = jb2 | (t + (t >= ib2 ? 1 : 0));
    const float* kp = s_k + (asl*8)*33 + jl;
    float s = aq0.x*kp[0]  + aq0.y*kp[33]  + aq0.z*kp[66]  + aq0.w*kp[99]
            + aq1.x*kp[132] + aq1.y*kp[165] + aq1.z*kp[198] + aq1.w*kp[231];
    s += __shfl_xor(s, 1); s += __shfl_xor(s, 2); s += __shfl_xor(s, 4);
    sc[t] = s * 0.125f;
  }
  {
    float m = sc[0];
    #pragma unroll
    for (int t = 1; t < 15; t++) m = fmaxf(m, sc[t]);
    float den = 0.f;
    #pragma unroll
    for (int t = 0; t < 15; t++) den += __expf(sc[t]-m);
    float rden = rcpf(den);
    const float bh0 = ws[OFF_BHARD], bh1 = ws[OFF_BHARD+1];
    const float* yF = ws + OFF_YF; const float* yB = ws + OFF_YB;
    #pragma unroll
    for (int t = 0; t < 15; t++){
      if ((t & 7) == asl){
        int rowb = ((base + n2)*15 + t)*2;
        float y0 = yF[rowb]   + yB[rowb]   + bh0;
        float y1 = yF[rowb+1] + yB[rowb+1] + bh1;
        float2 u2 = *(const float2*)&gum[rowb];
        float g0 = -__logf(-__logf(u2.x + EPSG) + EPSG);
        float g1 = -__logf(-__logf(u2.y + EPSG) + EPSG);
        float w  = sigf(((y1+g1) - (y0+g0)) * (1.0f/TAU_));
        s_co[t*32 + n2] = __expf(sc[t]-m)*rden*w;
      }
    }
  }
  __syncthreads();

  // F: x = sum_t coeff * v  (8 a's per thread), write x bf16 frags; stage h0
  {
    float xa[8];
    #pragma unroll
    for (int il = 0; il < 8; il++) xa[il] = 0.f;
    #pragma unroll
    for (int t = 0; t < 15; t++){
      float c = s_co[t*32 + n2];
      int jl = jb2 | (t + (t >= ib2 ? 1 : 0));
      const float* vp = s_v + (asl*8)*33 + jl;
      xa[0] += c*vp[0];    xa[1] += c*vp[33];   xa[2] += c*vp[66];   xa[3] += c*vp[99];
      xa[4] += c*vp[132];  xa[5] += c*vp[165];  xa[6] += c*vp[198];  xa[7] += c*vp[231];
    }
    union { v8s v; unsigned short u[8]; } XH, XL;
    #pragma unroll
    for (int e = 0; e < 8; e++){
      XH.u[e] = f2bf(xa[e]);
      XL.u[e] = f2bf(xa[e] - bf2f(XH.u[e]));
    }
    *(v8s*)&s_xh[n2*72 + asl*8] = XH.v;
    *(v8s*)&s_xl[n2*72 + asl*8] = XL.v;
  }
  {
    float4 a = *(const float4*)&hid[base*64 + tid*8];
    float4 b = *(const float4*)&hid[base*64 + tid*8 + 4];
    int nn = tid >> 3, d0 = (tid & 7)*8;
    union { v8s v; unsigned short u[8]; } H, L;
    float xs[8] = {a.x,a.y,a.z,a.w,b.x,b.y,b.z,b.w};
    #pragma unroll
    for (int e = 0; e < 8; e++){
      H.u[e] = f2bf(xs[e]);
      L.u[e] = f2bf(xs[e] - bf2f(H.u[e]));
    }
    *(v8s*)&s_h0h[nn*72 + d0] = H.v;
    *(v8s*)&s_h0l[nn*72 + d0] = L.v;
  }
  __syncthreads();

  // G: final GRU cell via MFMA: gi = Wihc.x, gh = Whhc.h0
  v8s xbH[2], xbL[2], h0H[2], h0L[2];
  #pragma unroll
  for (int kc = 0; kc < 2; kc++){
    int ba = node*72 + kc*32 + q4*8;
    xbH[kc] = *(const v8s*)&s_xh[ba];  xbL[kc] = *(const v8s*)&s_xl[ba];
    h0H[kc] = *(const v8s*)&s_h0h[ba]; h0L[kc] = *(const v8s*)&s_h0l[ba];
  }
  const unsigned short* wiH = (const unsigned short*)(ws + OFF_WIHC_H);
  const unsigned short* wiL = (const unsigned short*)(ws + OFF_WIHC_L);
  const unsigned short* whH = (const unsigned short*)(ws + OFF_WHHC_H);
  const unsigned short* whL = (const unsigned short*)(ws + OFF_WHHC_L);
  const float* bihc = ws + OFF_BIHC; const float* bhhc = ws + OFF_BHHC;
  v4f gi[3][2], gh[3][2];
  #pragma unroll
  for (int g = 0; g < 3; g++){
    #pragma unroll
    for (int u2 = 0; u2 < 2; u2++){
      int u = 2*lw + u2;
      int row0 = g*64 + 16*u + 4*q4;
      float4 bi = *(const float4*)&bihc[row0];
      float4 bh = *(const float4*)&bhhc[row0];
      v4f di, dh;
      if (g < 2){
        di = (v4f){bi.x+bh.x, bi.y+bh.y, bi.z+bh.z, bi.w+bh.w};
        dh = (v4f){0.f,0.f,0.f,0.f};
      } else {
        di = (v4f){bi.x, bi.y, bi.z, bi.w};
        dh = (v4f){bh.x, bh.y, bh.z, bh.w};
      }
      #pragma unroll
      for (int kc = 0; kc < 2; kc++){
        int ai = (g*64 + 16*u + i_c)*64 + kc*32 + q4*8;
        v8s aH = *(const v8s*)&wiH[ai]; v8s aL = *(const v8s*)&wiL[ai];
        di = __builtin_amdgcn_mfma_f32_16x16x32_bf16(aH, xbH[kc], di, 0,0,0);
        di = __builtin_amdgcn_mfma_f32_16x16x32_bf16(aH, xbL[kc], di, 0,0,0);
        di = __builtin_amdgcn_mfma_f32_16x16x32_bf16(aL, xbH[kc], di, 0,0,0);
        aH = *(const v8s*)&whH[ai]; aL = *(const v8s*)&whL[ai];
        dh = __builtin_amdgcn_mfma_f32_16x16x32_bf16(aH, h0H[kc], dh, 0,0,0);
        dh = __builtin_amdgcn_mfma_f32_16x16x32_bf16(aH, h0L[kc], dh, 0,0,0);
        dh = __builtin_amdgcn_mfma_f32_16x16x32_bf16(aL, h0H[kc], dh, 0,0,0);
      }
      gi[g][u2] = di; gh[g][u2] = dh;
    }
  }
  #pragma unroll
  for (int u2 = 0; u2 < 2; u2++){
    int l0 = 16*(2*lw + u2) + 4*q4;
    float4 h04 = *(const float4*)&hid[(base+node)*64 + l0];
    float hh[4] = {h04.x, h04.y, h04.z, h04.w};
    float ho[4];
    #pragma unroll
    for (int r = 0; r < 4; r++){
      float rg = sigf(gi[0][u2][r] + gh[0][u2][r]);
      float zg = sigf(gi[1][u2][r] + gh[1][u2][r]);
      float ng = tanhfast(gi[2][u2][r] + rg*gh[2][u2][r]);
      ho[r] = (1.0f - zg)*ng + zg*hh[r];
    }
    *(float4*)&out[(base+node)*64 + l0] = make_float4(ho[0], ho[1], ho[2], ho[3]);
  }
}

extern "C" void kernel_launch(void* const* d_in, const int* in_sizes, int n_in,
                              void* d_out, int out_size, void* d_ws, size_t ws_size,
                              hipStream_t stream){
  if (ws_size < (size_t)WS_FLOATS * sizeof(float)) return;
  float* ws = (float*)d_ws;
  // f32 copies still needed; MFMA weights go through k_prep2 bf16 splits
  static const int offs[20] = {OFF_WENC, OFF_BENC, 0, 0, OFF_BIHF, OFF_BHHF,
      0, 0, OFF_BIHB, OFF_BHHB, OFF_WHARD, OFF_BHARD, 0, 0, 0,
      OFF_BV, 0, 0, OFF_BIHC, OFF_BHHC};
  Prep p;
  for (int i = 0; i < 20; i++){
    p.s[i] = (const float*)d_in[3 + i];
    p.n[i] = in_sizes[3 + i];
    p.o[i] = offs[i];
  }
  // zero out f32 copies replaced by bf16 splits:
  p.n[2] = 0; p.n[3] = 0; p.n[6] = 0; p.n[7] = 0;      // Wih_f/Whh_f/Wih_b/Whh_b
  p.n[12] = 0; p.n[13] = 0; p.n[14] = 0;               // Wq/Wk/Wv
  p.n[16] = 0; p.n[17] = 0;                            // Wih_c/Whh_c
  hipLaunchKernelGGL(k_prep, dim3(96, 20), dim3(256), 0, stream, p, ws);
  hipLaunchKernelGGL(k_prep2, dim3(96, 10), dim3(256), 0, stream,
                     (const float*)d_in[3], (const float*)d_in[5], (const float*)d_in[9],
                     (const float*)d_in[6], (const float*)d_in[10],
                     (const float*)d_in[15], (const float*)d_in[16], (const float*)d_in[17],
                     (const float*)d_in[19], (const float*)d_in[20], ws);
  hipLaunchKernelGGL(k_gru,  dim3(1024),   dim3(256), 0, stream,
                     (const float*)d_in[0], ws);
  hipLaunchKernelGGL(k_attn, dim3(512),    dim3(256), 0, stream,
                     (const float*)d_in[0], (const float*)d_in[1],
                     (const float*)d_in[2], ws, (float*)d_out);
}